// Round 8
// baseline (248.564 us; speedup 1.0000x reference)
//
#include <hip/hip_runtime.h>

#define D 64
#define BK_SHIFT 8
#define BK_MASK 255
#define SEGCAP 4096
#define ESLICE 4096

typedef __attribute__((ext_vector_type(8))) short short8;   // 8 bf16 = 4 VGPRs
typedef __attribute__((ext_vector_type(4))) float floatx4;  // MFMA C/D

__device__ __forceinline__ ushort f2bf(float f) {     // fp32 -> bf16, RNE
    unsigned u = __float_as_uint(f);
    u += 0x7fffu + ((u >> 16) & 1u);
    return (ushort)(u >> 16);
}
__device__ __forceinline__ float bf2f(ushort h) {
    return __int_as_float(((unsigned)h) << 16);
}

// ---------------- fused: cast x to bf16 rows (blocks < castb) ---------------------
//                  + bucket counts of dst>>8 (blocks >= castb) ---------------------
// Independent phases overlap; bkcnt/hist/bincur0 pre-zeroed by hipMemsetAsync.
__global__ void cast_bkcount_kernel(const float* __restrict__ x, ushort* __restrict__ xh,
                                    const int* __restrict__ ei, int* __restrict__ bkcnt,
                                    int n4, int E, int B, int castb) {
    int bid = blockIdx.x;
    int tid = threadIdx.x;
    if (bid < castb) {                       // ---- cast role
        int i = bid * 256 + tid;
        if (i >= n4) return;
        float4 v = ((const float4*)x)[i];
        ushort4 r;
        r.x = f2bf(v.x); r.y = f2bf(v.y); r.z = f2bf(v.z); r.w = f2bf(v.w);
        ((ushort4*)xh)[i] = r;
        return;
    }
    // ---- bkcount role: per-block LDS hist of dst>>8 -> global bucket counts
    __shared__ int h[512];
    h[tid] = 0; h[tid + 256] = 0;
    __syncthreads();
    int e0 = (bid - castb) * ESLICE;
#pragma unroll 4
    for (int it = 0; it < ESLICE / 256; ++it) {
        int e = e0 + it * 256 + tid;
        if (e < E) atomicAdd(&h[ei[E + e] >> BK_SHIFT], 1);
    }
    __syncthreads();
    if (tid < B && h[tid]) atomicAdd(&bkcnt[tid], h[tid]);
    int t2 = tid + 256;
    if (t2 < B && h[t2]) atomicAdd(&bkcnt[t2], h[t2]);
}

// ---------------- A2: single-block exclusive scan of bucket counts ----------------
__global__ void bkscan_kernel(const int* __restrict__ bkcnt, int* __restrict__ bkbeg,
                              int* __restrict__ bkcur, int B) {
    __shared__ int wsum[8];
    int tid = threadIdx.x;           // 512 threads
    int lane = tid & 63, w = tid >> 6;
    int c = (tid < B) ? bkcnt[tid] : 0;
    int p = c;
#pragma unroll
    for (int o = 1; o < 64; o <<= 1) {
        int u = __shfl_up(p, o, 64);
        if (lane >= o) p += u;
    }
    if (lane == 63) wsum[w] = p;
    __syncthreads();
    int base = 0;
    for (int ww = 0; ww < w; ++ww) base += wsum[ww];
    int excl = base + p - c;
    if (tid < B) { bkbeg[tid] = excl; bkcur[tid] = excl; }
    if (tid == B - 1) bkbeg[B] = excl + c;   // == E
}

// ---------------- A3: route edges into bucket regions, packed (src<<8)|dstlow -----
__global__ void route_kernel(const int* __restrict__ ei, int* __restrict__ bkcur,
                             int* __restrict__ bucketed, int E, int B) {
    __shared__ int h[512];
    __shared__ int gb[512];
    int tid = threadIdx.x;
    h[tid] = 0; h[tid + 256] = 0;
    __syncthreads();
    int e0 = blockIdx.x * ESLICE;
#pragma unroll 4
    for (int it = 0; it < ESLICE / 256; ++it) {  // pass 1: local hist
        int e = e0 + it * 256 + tid;
        if (e < E) atomicAdd(&h[ei[E + e] >> BK_SHIFT], 1);
    }
    __syncthreads();
    if (tid < B) gb[tid] = h[tid] ? atomicAdd(&bkcur[tid], h[tid]) : 0;
    int t2 = tid + 256;
    if (t2 < B) gb[t2] = h[t2] ? atomicAdd(&bkcur[t2], h[t2]) : 0;
    __syncthreads();
    h[tid] = 0; h[tid + 256] = 0;                // reuse as pass-2 cursors
    __syncthreads();
#pragma unroll 4
    for (int it = 0; it < ESLICE / 256; ++it) {  // pass 2: route (dst slice L2-hot)
        int e = e0 + it * 256 + tid;
        if (e < E) {
            int dst = ei[E + e];
            int key = dst >> BK_SHIFT;
            int src = ei[e];
            int r = atomicAdd(&h[key], 1);
            bucketed[gb[key] + r] = (src << BK_SHIFT) | (dst & BK_MASK);
        }
    }
}

// ---------------- B: per-bucket CSR segment build, all HBM writes coalesced -------
__global__ void csr_kernel(const int* __restrict__ bucketed, const int* __restrict__ bkbeg,
                           int* __restrict__ srclist, int* __restrict__ beg,
                           int* __restrict__ cnt, int* __restrict__ hist, int N) {
    __shared__ int lcnt[256];
    __shared__ int lbeg[256];
    __shared__ int seg[SEGCAP];
    __shared__ int wsum[4];
    __shared__ int lh[64];
    int k = blockIdx.x;
    int tid = threadIdx.x;
    int nd0 = k << BK_SHIFT;
    int nn = min(256, N - nd0);
    int ebeg = bkbeg[k], eend = bkbeg[k + 1];
    int ecnt = eend - ebeg;
    lcnt[tid] = 0;
    if (tid < 64) lh[tid] = 0;
    __syncthreads();
    for (int e = ebeg + tid; e < eend; e += 256)
        atomicAdd(&lcnt[bucketed[e] & BK_MASK], 1);
    __syncthreads();
    int c = lcnt[tid];
    int lane = tid & 63, w = tid >> 6;
    int p = c;
#pragma unroll
    for (int o = 1; o < 64; o <<= 1) {
        int u = __shfl_up(p, o, 64);
        if (lane >= o) p += u;
    }
    if (lane == 63) wsum[w] = p;
    __syncthreads();
    int base = 0;
    for (int ww = 0; ww < w; ++ww) base += wsum[ww];
    int excl = base + p - c;
    lbeg[tid] = excl;
    lcnt[tid] = 0;                               // reuse as fill cursors
    __syncthreads();
    if (ecnt <= SEGCAP) {
        for (int e = ebeg + tid; e < eend; e += 256) {
            int v = bucketed[e];
            int key = v & BK_MASK;
            int pos = lbeg[key] + atomicAdd(&lcnt[key], 1);
            seg[pos] = v >> BK_SHIFT;
        }
        __syncthreads();
        for (int i = tid; i < ecnt; i += 256)
            srclist[ebeg + i] = seg[i];          // coalesced full-line dump
    } else {                                     // overflow fallback (correct, rare)
        for (int e = ebeg + tid; e < eend; e += 256) {
            int v = bucketed[e];
            int key = v & BK_MASK;
            int pos = lbeg[key] + atomicAdd(&lcnt[key], 1);
            srclist[ebeg + pos] = v >> BK_SHIFT;
        }
    }
    __syncthreads();
    if (tid < nn) {
        int dg = lcnt[tid];                      // cursor end == degree
        cnt[nd0 + tid] = dg;
        beg[nd0 + tid] = ebeg + lbeg[tid];
        atomicAdd(&lh[dg < 63 ? dg : 63], 1);
    }
    __syncthreads();
    if (tid < 64 && lh[tid]) atomicAdd(&hist[tid], lh[tid]);
}

// ---------------- scatter nodes into DESCENDING-degree perm ----------------------
__global__ void scatter_kernel(const int* __restrict__ cnt, const int* __restrict__ hist,
                               int* __restrict__ bincur0, int* __restrict__ perm, int N) {
    __shared__ int lh[64];
    __shared__ int lbase[64];
    __shared__ int sbase[64];
    int tid = threadIdx.x;
    if (tid < 64) {
        lh[tid] = 0;
        int c = hist[tid];
        int p = c;
#pragma unroll
        for (int o = 1; o < 64; o <<= 1) {
            int u = __shfl_up(p, o, 64);
            if (tid >= o) p += u;
        }
        sbase[tid] = N - p;            // suffix base: high-degree bins first
    }
    __syncthreads();
    int i = blockIdx.x * blockDim.x + tid;
    int bin = 0, slot = 0;
    if (i < N) {
        int c = cnt[i];
        bin = c < 63 ? c : 63;
        slot = atomicAdd(&lh[bin], 1);
    }
    __syncthreads();
    if (tid < 64 && lh[tid] > 0) lbase[tid] = sbase[tid] + atomicAdd(&bincur0[tid], lh[tid]);
    __syncthreads();
    if (i < N) perm[lbase[bin] + slot] = i;
}

// ---------------- fused SAGE layer: bf16 gather + MFMA combine ----------------
// 16 nodes per wave via degree-sorted perm. Gather is BATCHED 4 hops deep:
// explicit si0..3 -> lo/hi0..3 named registers force ~8 row-loads in flight per
// wave (round-5 diagnosis: VGPR_Count=64 let the compiler keep only ~2 loads
// outstanding -> latency-serialized at 13% VALUBusy). Grid = 1 group/wave,
// hardware backfill (1563 blocks beat 1024 grid-stride: 44.1 vs 46.9 us).
// launch_bounds(256,4): VGPR cap 128 (256,8@64 spilled: +150MB, never again).

__global__ void __launch_bounds__(256, 4) sage_kernel(
    const ushort* __restrict__ inh,      // bf16 rows [N][64]
    const int* __restrict__ perm,
    const int* __restrict__ beg_, const int* __restrict__ cnt_,
    const int* __restrict__ srclist,
    const float* __restrict__ Wl, const float* __restrict__ bl,
    const float* __restrict__ Wr,
    float* __restrict__ out_f32,         // fp32 out (layer 2) or null
    ushort* __restrict__ out_bf,         // bf16 out (layer 1) or null
    int N, int relu) {
    __shared__ short8 fL[8][64];   // [c*2+s][lane]: B-frag of Wl^T, col-tile c, k-step s
    __shared__ short8 fR[8][64];
    __shared__ float ot[4][16 * 68];     // per-wave out tile, stride 68 (bank spread)
    int tid = threadIdx.x;
    int lane = tid & 63;
    {
        int c = tid >> 6;
        int n = lane & 15;
        int q = lane >> 4;
#pragma unroll
        for (int s = 0; s < 2; ++s) {
            const float* pl = Wl + (c * 16 + n) * D + s * 32 + q * 8;
            const float* pr = Wr + (c * 16 + n) * D + s * 32 + q * 8;
            short8 vl, vr;
#pragma unroll
            for (int j = 0; j < 8; ++j) {
                vl[j] = (short)f2bf(pl[j]);
                vr[j] = (short)f2bf(pr[j]);
            }
            fL[c * 2 + s][lane] = vl;
            fR[c * 2 + s][lane] = vr;
        }
    }
    __syncthreads();

    int m = lane & 15;
    int q = lane >> 4;
    float* otw = &ot[tid >> 6][0];
    float b0 = bl[m], b1 = bl[16 + m], b2 = bl[32 + m], b3 = bl[48 + m];
    int gwave   = blockIdx.x * 4 + (tid >> 6);
    int nwaves  = gridDim.x * 4;
    int ngroups = (N + 15) >> 4;

    for (int g = gwave; g < ngroups; g += nwaves) {
        int base = g * 16;
        bool nv = (base + m) < N;
        int node = nv ? perm[base + m] : 0;
        int beg = nv ? beg_[node] : 0;   // 4 lanes per node share the address
        int deg = nv ? cnt_[node] : 0;

        // wave-max degree (uniform after descending sort except at bin boundaries)
        int md = deg;
        md = max(md, __shfl_xor(md, 1, 64));
        md = max(md, __shfl_xor(md, 2, 64));
        md = max(md, __shfl_xor(md, 4, 64));
        md = max(md, __shfl_xor(md, 8, 64));

        float f0[8], f1[8];
#pragma unroll
        for (int u = 0; u < 8; ++u) { f0[u] = 0.f; f1[u] = 0.f; }

        // batched gather: 4 hops per stage -> ~8 row loads in flight per wave
        for (int j = 0; j < md; j += 4) {
            int si0, si1, si2, si3;
            {
                int j0 = j,     i0 = beg + ((j0 < deg) ? j0 : 0);
                int j1 = j + 1, i1 = beg + ((j1 < deg) ? j1 : 0);
                int j2 = j + 2, i2 = beg + ((j2 < deg) ? j2 : 0);
                int j3 = j + 3, i3 = beg + ((j3 < deg) ? j3 : 0);
                si0 = srclist[i0]; si1 = srclist[i1];
                si2 = srclist[i2]; si3 = srclist[i3];
            }
            const ushort* rp0 = inh + (size_t)si0 * D;
            const ushort* rp1 = inh + (size_t)si1 * D;
            const ushort* rp2 = inh + (size_t)si2 * D;
            const ushort* rp3 = inh + (size_t)si3 * D;
            short8 lo0 = *(const short8*)(rp0 + q * 8);
            short8 hi0 = *(const short8*)(rp0 + 32 + q * 8);
            short8 lo1 = *(const short8*)(rp1 + q * 8);
            short8 hi1 = *(const short8*)(rp1 + 32 + q * 8);
            short8 lo2 = *(const short8*)(rp2 + q * 8);
            short8 hi2 = *(const short8*)(rp2 + 32 + q * 8);
            short8 lo3 = *(const short8*)(rp3 + q * 8);
            short8 hi3 = *(const short8*)(rp3 + 32 + q * 8);
            float m0 = (j     < deg) ? 1.f : 0.f;
            float m1 = (j + 1 < deg) ? 1.f : 0.f;
            float m2 = (j + 2 < deg) ? 1.f : 0.f;
            float m3 = (j + 3 < deg) ? 1.f : 0.f;
#pragma unroll
            for (int u = 0; u < 8; ++u) {
                f0[u] = fmaf(m0, bf2f((ushort)lo0[u]), f0[u]);
                f1[u] = fmaf(m0, bf2f((ushort)hi0[u]), f1[u]);
                f0[u] = fmaf(m1, bf2f((ushort)lo1[u]), f0[u]);
                f1[u] = fmaf(m1, bf2f((ushort)hi1[u]), f1[u]);
                f0[u] = fmaf(m2, bf2f((ushort)lo2[u]), f0[u]);
                f1[u] = fmaf(m2, bf2f((ushort)hi2[u]), f1[u]);
                f0[u] = fmaf(m3, bf2f((ushort)lo3[u]), f0[u]);
                f1[u] = fmaf(m3, bf2f((ushort)hi3[u]), f1[u]);
            }
        }

        float scale = (deg > 0) ? 1.0f / (float)deg : 0.0f;
        short8 a0, a1;
#pragma unroll
        for (int u = 0; u < 8; ++u) {
            a0[u] = (short)f2bf(f0[u] * scale);
            a1[u] = (short)f2bf(f1[u] * scale);
        }

        // root rows load directly as A-fragments
        const ushort* rr = inh + (size_t)node * D;
        short8 r0 = *(const short8*)(rr + q * 8);
        short8 r1 = *(const short8*)(rr + 32 + q * 8);

#pragma unroll
        for (int c = 0; c < 4; ++c) {
            float bc = (c == 0) ? b0 : (c == 1) ? b1 : (c == 2) ? b2 : b3;
            floatx4 acc = {bc, bc, bc, bc};
            acc = __builtin_amdgcn_mfma_f32_16x16x32_bf16(a0, fL[c * 2 + 0][lane], acc, 0, 0, 0);
            acc = __builtin_amdgcn_mfma_f32_16x16x32_bf16(a1, fL[c * 2 + 1][lane], acc, 0, 0, 0);
            acc = __builtin_amdgcn_mfma_f32_16x16x32_bf16(r0, fR[c * 2 + 0][lane], acc, 0, 0, 0);
            acc = __builtin_amdgcn_mfma_f32_16x16x32_bf16(r1, fR[c * 2 + 1][lane], acc, 0, 0, 0);
#pragma unroll
            for (int r = 0; r < 4; ++r) {
                float v = acc[r];
                if (relu) v = fmaxf(v, 0.f);
                otw[(q * 4 + r) * 68 + c * 16 + m] = v;   // stage in LDS (wave-private)
            }
        }

        // full-row writeout: 4 lanes per node row, line-complete stores
        int rho = lane >> 2;                 // node slot 0..15
        int q4  = lane & 3;                  // quarter of the row
        int onode = __shfl(node, rho, 64);
        const float* sp = &otw[rho * 68 + q4 * 16];
        if (base + rho < N) {
            if (out_bf) {
                uint u[8];
#pragma unroll
                for (int j = 0; j < 8; ++j)
                    u[j] = (uint)f2bf(sp[2 * j]) | ((uint)f2bf(sp[2 * j + 1]) << 16);
                uint4* dp = (uint4*)(out_bf + (size_t)onode * D + q4 * 16);
                uint4 w0 = {u[0], u[1], u[2], u[3]};
                uint4 w1 = {u[4], u[5], u[6], u[7]};
                dp[0] = w0; dp[1] = w1;      // 32B/lane, 128B/row contiguous
            } else {
                float4* dp = (float4*)(out_f32 + (size_t)onode * D + q4 * 16);
                const float4* s4 = (const float4*)sp;
                dp[0] = s4[0]; dp[1] = s4[1]; dp[2] = s4[2]; dp[3] = s4[3];  // 64B/lane
            }
        }
    }
}

extern "C" void kernel_launch(void* const* d_in, const int* in_sizes, int n_in,
                              void* d_out, int out_size, void* d_ws, size_t ws_size,
                              hipStream_t stream) {
    const float* x   = (const float*)d_in[0];
    const int*   ei  = (const int*)d_in[1];
    const float* W1l = (const float*)d_in[2];
    const float* b1l = (const float*)d_in[3];
    const float* W1r = (const float*)d_in[4];
    const float* W2l = (const float*)d_in[5];
    const float* b2l = (const float*)d_in[6];
    const float* W2r = (const float*)d_in[7];
    float* out = (float*)d_out;

    int N = in_sizes[0] / D;   // 100000
    int E = in_sizes[1] / 2;   // 1000000
    int B = (N + BK_MASK) >> BK_SHIFT;   // 391 buckets

    char* ws = (char*)d_ws;
    // Layout (bytes):
    //   [0, N*D*2)         xh : bf16 x rows
    //   [N*D*2, 2*N*D*2)   hh : bf16 h rows; `bucketed` (E ints = 4MB < 12.8MB)
    //                          aliases here -- dead before sage1 writes hh
    //   then srclist (+slack), beg, cnt, perm.
    //   hist, bincur0, bkcnt are contiguous and cleared by ONE memset.
    ushort* xh = (ushort*)ws;
    ushort* hh = xh + (size_t)N * D;
    int*   bucketed = (int*)hh;                           // E ints (alias hh)
    int*   srclist  = (int*)(ws + (size_t)2 * N * D * 2); // E ints + 64 slack
    int*   beg      = srclist + E + 64;                   // N ints
    int*   cnt      = beg + N;                            // N ints
    int*   perm     = cnt + N;                            // N ints
    int*   hist     = perm + N;                           // 64 ints (memset group)
    int*   bincur0  = hist + 64;                          // 64 ints (memset group)
    int*   bkcnt    = bincur0 + 64;                       // 512 ints (memset group)
    int*   bkbeg    = bkcnt + 512;                        // 513 ints
    int*   bkcur    = bkbeg + 513;                        // 512 ints

    (void)hipMemsetAsync(hist, 0, (64 + 64 + 512) * sizeof(int), stream);

    int n4 = N * D / 4;
    int castb = (n4 + 255) / 256;
    int eslices = (E + ESLICE - 1) / ESLICE;
    cast_bkcount_kernel<<<castb + eslices, 256, 0, stream>>>(x, xh, ei, bkcnt,
                                                             n4, E, B, castb);
    bkscan_kernel<<<1, 512, 0, stream>>>(bkcnt, bkbeg, bkcur, B);
    route_kernel<<<eslices, 256, 0, stream>>>(ei, bkcur, bucketed, E, B);
    csr_kernel<<<B, 256, 0, stream>>>(bucketed, bkbeg, srclist, beg, cnt, hist, N);
    int nblocks = (N + 255) / 256;
    scatter_kernel<<<nblocks, 256, 0, stream>>>(cnt, hist, bincur0, perm, N);

    int ngroups = (N + 15) / 16;              // 6250
    int sblocks = (ngroups + 3) / 4;          // 1 group per wave, HW backfill
    // layer 1: hh(bf16) = relu(mean_agg(xh)@W1l^T + b1l + xh@W1r^T)
    sage_kernel<<<sblocks, 256, 0, stream>>>(xh, perm, beg, cnt, srclist,
                                             W1l, b1l, W1r, nullptr, hh, N, 1);
    // layer 2: out(fp32) = mean_agg(hh)@W2l^T + b2l + hh@W2r^T
    sage_kernel<<<sblocks, 256, 0, stream>>>(hh, perm, beg, cnt, srclist,
                                             W2l, b2l, W2r, out, nullptr, N, 0);
}

// Round 9
// 218.648 us; speedup vs baseline: 1.1368x; 1.1368x over previous
//
#include <hip/hip_runtime.h>

#define D 64
#define BK_SHIFT 8
#define BK_MASK 255
#define SEGCAP 4096
#define ESLICE 4096

typedef __attribute__((ext_vector_type(8))) short short8;   // 8 bf16 = 4 VGPRs
typedef __attribute__((ext_vector_type(4))) float floatx4;  // MFMA C/D

__device__ __forceinline__ ushort f2bf(float f) {     // fp32 -> bf16, RNE
    unsigned u = __float_as_uint(f);
    u += 0x7fffu + ((u >> 16) & 1u);
    return (ushort)(u >> 16);
}
__device__ __forceinline__ float bf2f(ushort h) {
    return __int_as_float(((unsigned)h) << 16);
}

// ---------------- fused: cast x to bf16 rows (blocks < castb) ---------------------
//                  + bucket counts of dst>>8 (blocks >= castb) ---------------------
// Independent phases overlap; bkcnt/hist/bincur0 pre-zeroed by hipMemsetAsync.
__global__ void cast_bkcount_kernel(const float* __restrict__ x, ushort* __restrict__ xh,
                                    const int* __restrict__ ei, int* __restrict__ bkcnt,
                                    int n4, int E, int B, int castb) {
    int bid = blockIdx.x;
    int tid = threadIdx.x;
    if (bid < castb) {                       // ---- cast role
        int i = bid * 256 + tid;
        if (i >= n4) return;
        float4 v = ((const float4*)x)[i];
        ushort4 r;
        r.x = f2bf(v.x); r.y = f2bf(v.y); r.z = f2bf(v.z); r.w = f2bf(v.w);
        ((ushort4*)xh)[i] = r;
        return;
    }
    // ---- bkcount role: per-block LDS hist of dst>>8 -> global bucket counts
    __shared__ int h[512];
    h[tid] = 0; h[tid + 256] = 0;
    __syncthreads();
    int e0 = (bid - castb) * ESLICE;
#pragma unroll 4
    for (int it = 0; it < ESLICE / 256; ++it) {
        int e = e0 + it * 256 + tid;
        if (e < E) atomicAdd(&h[ei[E + e] >> BK_SHIFT], 1);
    }
    __syncthreads();
    if (tid < B && h[tid]) atomicAdd(&bkcnt[tid], h[tid]);
    int t2 = tid + 256;
    if (t2 < B && h[t2]) atomicAdd(&bkcnt[t2], h[t2]);
}

// ---------------- A2: single-block exclusive scan of bucket counts ----------------
__global__ void bkscan_kernel(const int* __restrict__ bkcnt, int* __restrict__ bkbeg,
                              int* __restrict__ bkcur, int B) {
    __shared__ int wsum[8];
    int tid = threadIdx.x;           // 512 threads
    int lane = tid & 63, w = tid >> 6;
    int c = (tid < B) ? bkcnt[tid] : 0;
    int p = c;
#pragma unroll
    for (int o = 1; o < 64; o <<= 1) {
        int u = __shfl_up(p, o, 64);
        if (lane >= o) p += u;
    }
    if (lane == 63) wsum[w] = p;
    __syncthreads();
    int base = 0;
    for (int ww = 0; ww < w; ++ww) base += wsum[ww];
    int excl = base + p - c;
    if (tid < B) { bkbeg[tid] = excl; bkcur[tid] = excl; }
    if (tid == B - 1) bkbeg[B] = excl + c;   // == E
}

// ---------------- A3: route edges into bucket regions, packed (src<<8)|dstlow -----
__global__ void route_kernel(const int* __restrict__ ei, int* __restrict__ bkcur,
                             int* __restrict__ bucketed, int E, int B) {
    __shared__ int h[512];
    __shared__ int gb[512];
    int tid = threadIdx.x;
    h[tid] = 0; h[tid + 256] = 0;
    __syncthreads();
    int e0 = blockIdx.x * ESLICE;
#pragma unroll 4
    for (int it = 0; it < ESLICE / 256; ++it) {  // pass 1: local hist
        int e = e0 + it * 256 + tid;
        if (e < E) atomicAdd(&h[ei[E + e] >> BK_SHIFT], 1);
    }
    __syncthreads();
    if (tid < B) gb[tid] = h[tid] ? atomicAdd(&bkcur[tid], h[tid]) : 0;
    int t2 = tid + 256;
    if (t2 < B) gb[t2] = h[t2] ? atomicAdd(&bkcur[t2], h[t2]) : 0;
    __syncthreads();
    h[tid] = 0; h[tid + 256] = 0;                // reuse as pass-2 cursors
    __syncthreads();
#pragma unroll 4
    for (int it = 0; it < ESLICE / 256; ++it) {  // pass 2: route (dst slice L2-hot)
        int e = e0 + it * 256 + tid;
        if (e < E) {
            int dst = ei[E + e];
            int key = dst >> BK_SHIFT;
            int src = ei[e];
            int r = atomicAdd(&h[key], 1);
            bucketed[gb[key] + r] = (src << BK_SHIFT) | (dst & BK_MASK);
        }
    }
}

// ---------------- B: per-bucket CSR segment build, all HBM writes coalesced -------
__global__ void csr_kernel(const int* __restrict__ bucketed, const int* __restrict__ bkbeg,
                           int* __restrict__ srclist, int* __restrict__ beg,
                           int* __restrict__ cnt, int* __restrict__ hist, int N) {
    __shared__ int lcnt[256];
    __shared__ int lbeg[256];
    __shared__ int seg[SEGCAP];
    __shared__ int wsum[4];
    __shared__ int lh[64];
    int k = blockIdx.x;
    int tid = threadIdx.x;
    int nd0 = k << BK_SHIFT;
    int nn = min(256, N - nd0);
    int ebeg = bkbeg[k], eend = bkbeg[k + 1];
    int ecnt = eend - ebeg;
    lcnt[tid] = 0;
    if (tid < 64) lh[tid] = 0;
    __syncthreads();
    for (int e = ebeg + tid; e < eend; e += 256)
        atomicAdd(&lcnt[bucketed[e] & BK_MASK], 1);
    __syncthreads();
    int c = lcnt[tid];
    int lane = tid & 63, w = tid >> 6;
    int p = c;
#pragma unroll
    for (int o = 1; o < 64; o <<= 1) {
        int u = __shfl_up(p, o, 64);
        if (lane >= o) p += u;
    }
    if (lane == 63) wsum[w] = p;
    __syncthreads();
    int base = 0;
    for (int ww = 0; ww < w; ++ww) base += wsum[ww];
    int excl = base + p - c;
    lbeg[tid] = excl;
    lcnt[tid] = 0;                               // reuse as fill cursors
    __syncthreads();
    if (ecnt <= SEGCAP) {
        for (int e = ebeg + tid; e < eend; e += 256) {
            int v = bucketed[e];
            int key = v & BK_MASK;
            int pos = lbeg[key] + atomicAdd(&lcnt[key], 1);
            seg[pos] = v >> BK_SHIFT;
        }
        __syncthreads();
        for (int i = tid; i < ecnt; i += 256)
            srclist[ebeg + i] = seg[i];          // coalesced full-line dump
    } else {                                     // overflow fallback (correct, rare)
        for (int e = ebeg + tid; e < eend; e += 256) {
            int v = bucketed[e];
            int key = v & BK_MASK;
            int pos = lbeg[key] + atomicAdd(&lcnt[key], 1);
            srclist[ebeg + pos] = v >> BK_SHIFT;
        }
    }
    __syncthreads();
    if (tid < nn) {
        int dg = lcnt[tid];                      // cursor end == degree
        cnt[nd0 + tid] = dg;
        beg[nd0 + tid] = ebeg + lbeg[tid];
        atomicAdd(&lh[dg < 63 ? dg : 63], 1);
    }
    __syncthreads();
    if (tid < 64 && lh[tid]) atomicAdd(&hist[tid], lh[tid]);
}

// ---------------- scatter nodes into DESCENDING-degree perm ----------------------
__global__ void scatter_kernel(const int* __restrict__ cnt, const int* __restrict__ hist,
                               int* __restrict__ bincur0, int* __restrict__ perm, int N) {
    __shared__ int lh[64];
    __shared__ int lbase[64];
    __shared__ int sbase[64];
    int tid = threadIdx.x;
    if (tid < 64) {
        lh[tid] = 0;
        int c = hist[tid];
        int p = c;
#pragma unroll
        for (int o = 1; o < 64; o <<= 1) {
            int u = __shfl_up(p, o, 64);
            if (tid >= o) p += u;
        }
        sbase[tid] = N - p;            // suffix base: high-degree bins first
    }
    __syncthreads();
    int i = blockIdx.x * blockDim.x + tid;
    int bin = 0, slot = 0;
    if (i < N) {
        int c = cnt[i];
        bin = c < 63 ? c : 63;
        slot = atomicAdd(&lh[bin], 1);
    }
    __syncthreads();
    if (tid < 64 && lh[tid] > 0) lbase[tid] = sbase[tid] + atomicAdd(&bincur0[tid], lh[tid]);
    __syncthreads();
    if (i < N) perm[lbase[bin] + slot] = i;
}

// ---------------- fused SAGE layer: bf16 gather + MFMA combine ----------------
// 16 nodes per wave via degree-sorted perm. Gather loop = round-4 body (44us,
// VGPR 64, no spill). Round-8 lesson: hand-batching 4 hops spilled at CONSTANT
// VGPR_Count=64 (WRITE 37->94MB) -- the unified-file budget at (256,4)=128 is
// consumed by the AGPR/accumulator side, so the allocator has no slack.
// This round: launch_bounds(256,3) raises the total cap to 170 so the compiler
// can pipeline the unrolled loop itself; LDS (33792) still allows 4 blocks/CU
// if the allocation stays <= 128.

__global__ void __launch_bounds__(256, 3) sage_kernel(
    const ushort* __restrict__ inh,      // bf16 rows [N][64]
    const int* __restrict__ perm,
    const int* __restrict__ beg_, const int* __restrict__ cnt_,
    const int* __restrict__ srclist,
    const float* __restrict__ Wl, const float* __restrict__ bl,
    const float* __restrict__ Wr,
    float* __restrict__ out_f32,         // fp32 out (layer 2) or null
    ushort* __restrict__ out_bf,         // bf16 out (layer 1) or null
    int N, int relu) {
    __shared__ short8 fL[8][64];   // [c*2+s][lane]: B-frag of Wl^T, col-tile c, k-step s
    __shared__ short8 fR[8][64];
    __shared__ float ot[4][16 * 68];     // per-wave out tile, stride 68 (bank spread)
    int tid = threadIdx.x;
    int lane = tid & 63;
    {
        int c = tid >> 6;
        int n = lane & 15;
        int q = lane >> 4;
#pragma unroll
        for (int s = 0; s < 2; ++s) {
            const float* pl = Wl + (c * 16 + n) * D + s * 32 + q * 8;
            const float* pr = Wr + (c * 16 + n) * D + s * 32 + q * 8;
            short8 vl, vr;
#pragma unroll
            for (int j = 0; j < 8; ++j) {
                vl[j] = (short)f2bf(pl[j]);
                vr[j] = (short)f2bf(pr[j]);
            }
            fL[c * 2 + s][lane] = vl;
            fR[c * 2 + s][lane] = vr;
        }
    }
    __syncthreads();

    int m = lane & 15;
    int q = lane >> 4;
    float* otw = &ot[tid >> 6][0];
    float b0 = bl[m], b1 = bl[16 + m], b2 = bl[32 + m], b3 = bl[48 + m];
    int gwave   = blockIdx.x * 4 + (tid >> 6);
    int nwaves  = gridDim.x * 4;
    int ngroups = (N + 15) >> 4;

    for (int g = gwave; g < ngroups; g += nwaves) {
        int base = g * 16;
        bool nv = (base + m) < N;
        int node = nv ? perm[base + m] : 0;
        int beg = nv ? beg_[node] : 0;   // 4 lanes per node share the address
        int deg = nv ? cnt_[node] : 0;

        // wave-max degree (uniform after descending sort except at bin boundaries)
        int md = deg;
        md = max(md, __shfl_xor(md, 1, 64));
        md = max(md, __shfl_xor(md, 2, 64));
        md = max(md, __shfl_xor(md, 4, 64));
        md = max(md, __shfl_xor(md, 8, 64));

        float f0[8], f1[8];
#pragma unroll
        for (int u = 0; u < 8; ++u) { f0[u] = 0.f; f1[u] = 0.f; }

#pragma unroll 8
        for (int j = 0; j < md; ++j) {
            int idx = beg + ((j < deg) ? j : 0);
            int si = srclist[idx];
            const ushort* rp = inh + (size_t)si * D;
            short8 lo = *(const short8*)(rp + q * 8);        // features q*8..+7
            short8 hi = *(const short8*)(rp + 32 + q * 8);   // features 32+q*8..+7
            float msk = (j < deg) ? 1.f : 0.f;
#pragma unroll
            for (int u = 0; u < 8; ++u) {
                f0[u] = fmaf(msk, bf2f((ushort)lo[u]), f0[u]);
                f1[u] = fmaf(msk, bf2f((ushort)hi[u]), f1[u]);
            }
        }

        float scale = (deg > 0) ? 1.0f / (float)deg : 0.0f;
        short8 a0, a1;
#pragma unroll
        for (int u = 0; u < 8; ++u) {
            a0[u] = (short)f2bf(f0[u] * scale);
            a1[u] = (short)f2bf(f1[u] * scale);
        }

        // root rows load directly as A-fragments
        const ushort* rr = inh + (size_t)node * D;
        short8 r0 = *(const short8*)(rr + q * 8);
        short8 r1 = *(const short8*)(rr + 32 + q * 8);

#pragma unroll
        for (int c = 0; c < 4; ++c) {
            float bc = (c == 0) ? b0 : (c == 1) ? b1 : (c == 2) ? b2 : b3;
            floatx4 acc = {bc, bc, bc, bc};
            acc = __builtin_amdgcn_mfma_f32_16x16x32_bf16(a0, fL[c * 2 + 0][lane], acc, 0, 0, 0);
            acc = __builtin_amdgcn_mfma_f32_16x16x32_bf16(a1, fL[c * 2 + 1][lane], acc, 0, 0, 0);
            acc = __builtin_amdgcn_mfma_f32_16x16x32_bf16(r0, fR[c * 2 + 0][lane], acc, 0, 0, 0);
            acc = __builtin_amdgcn_mfma_f32_16x16x32_bf16(r1, fR[c * 2 + 1][lane], acc, 0, 0, 0);
#pragma unroll
            for (int r = 0; r < 4; ++r) {
                float v = acc[r];
                if (relu) v = fmaxf(v, 0.f);
                otw[(q * 4 + r) * 68 + c * 16 + m] = v;   // stage in LDS (wave-private)
            }
        }

        // full-row writeout: 4 lanes per node row, line-complete stores
        int rho = lane >> 2;                 // node slot 0..15
        int q4  = lane & 3;                  // quarter of the row
        int onode = __shfl(node, rho, 64);
        const float* sp = &otw[rho * 68 + q4 * 16];
        if (base + rho < N) {
            if (out_bf) {
                uint u[8];
#pragma unroll
                for (int j = 0; j < 8; ++j)
                    u[j] = (uint)f2bf(sp[2 * j]) | ((uint)f2bf(sp[2 * j + 1]) << 16);
                uint4* dp = (uint4*)(out_bf + (size_t)onode * D + q4 * 16);
                uint4 w0 = {u[0], u[1], u[2], u[3]};
                uint4 w1 = {u[4], u[5], u[6], u[7]};
                dp[0] = w0; dp[1] = w1;      // 32B/lane, 128B/row contiguous
            } else {
                float4* dp = (float4*)(out_f32 + (size_t)onode * D + q4 * 16);
                const float4* s4 = (const float4*)sp;
                dp[0] = s4[0]; dp[1] = s4[1]; dp[2] = s4[2]; dp[3] = s4[3];  // 64B/lane
            }
        }
    }
}

extern "C" void kernel_launch(void* const* d_in, const int* in_sizes, int n_in,
                              void* d_out, int out_size, void* d_ws, size_t ws_size,
                              hipStream_t stream) {
    const float* x   = (const float*)d_in[0];
    const int*   ei  = (const int*)d_in[1];
    const float* W1l = (const float*)d_in[2];
    const float* b1l = (const float*)d_in[3];
    const float* W1r = (const float*)d_in[4];
    const float* W2l = (const float*)d_in[5];
    const float* b2l = (const float*)d_in[6];
    const float* W2r = (const float*)d_in[7];
    float* out = (float*)d_out;

    int N = in_sizes[0] / D;   // 100000
    int E = in_sizes[1] / 2;   // 1000000
    int B = (N + BK_MASK) >> BK_SHIFT;   // 391 buckets

    char* ws = (char*)d_ws;
    // Layout (bytes):
    //   [0, N*D*2)         xh : bf16 x rows
    //   [N*D*2, 2*N*D*2)   hh : bf16 h rows; `bucketed` (E ints = 4MB < 12.8MB)
    //                          aliases here -- dead before sage1 writes hh
    //   then srclist (+slack), beg, cnt, perm.
    //   hist, bincur0, bkcnt are contiguous and cleared by ONE memset.
    ushort* xh = (ushort*)ws;
    ushort* hh = xh + (size_t)N * D;
    int*   bucketed = (int*)hh;                           // E ints (alias hh)
    int*   srclist  = (int*)(ws + (size_t)2 * N * D * 2); // E ints + 64 slack
    int*   beg      = srclist + E + 64;                   // N ints
    int*   cnt      = beg + N;                            // N ints
    int*   perm     = cnt + N;                            // N ints
    int*   hist     = perm + N;                           // 64 ints (memset group)
    int*   bincur0  = hist + 64;                          // 64 ints (memset group)
    int*   bkcnt    = bincur0 + 64;                       // 512 ints (memset group)
    int*   bkbeg    = bkcnt + 512;                        // 513 ints
    int*   bkcur    = bkbeg + 513;                        // 512 ints

    (void)hipMemsetAsync(hist, 0, (64 + 64 + 512) * sizeof(int), stream);

    int n4 = N * D / 4;
    int castb = (n4 + 255) / 256;
    int eslices = (E + ESLICE - 1) / ESLICE;
    cast_bkcount_kernel<<<castb + eslices, 256, 0, stream>>>(x, xh, ei, bkcnt,
                                                             n4, E, B, castb);
    bkscan_kernel<<<1, 512, 0, stream>>>(bkcnt, bkbeg, bkcur, B);
    route_kernel<<<eslices, 256, 0, stream>>>(ei, bkcur, bucketed, E, B);
    csr_kernel<<<B, 256, 0, stream>>>(bucketed, bkbeg, srclist, beg, cnt, hist, N);
    int nblocks = (N + 255) / 256;
    scatter_kernel<<<nblocks, 256, 0, stream>>>(cnt, hist, bincur0, perm, N);

    int ngroups = (N + 15) / 16;              // 6250
    int sblocks = (ngroups + 3) / 4;          // 1 group per wave, HW backfill
    // layer 1: hh(bf16) = relu(mean_agg(xh)@W1l^T + b1l + xh@W1r^T)
    sage_kernel<<<sblocks, 256, 0, stream>>>(xh, perm, beg, cnt, srclist,
                                             W1l, b1l, W1r, nullptr, hh, N, 1);
    // layer 2: out(fp32) = mean_agg(hh)@W2l^T + b2l + hh@W2r^T
    sage_kernel<<<sblocks, 256, 0, stream>>>(hh, perm, beg, cnt, srclist,
                                             W2l, b2l, W2r, out, nullptr, N, 0);
}

// Round 10
// 217.503 us; speedup vs baseline: 1.1428x; 1.0053x over previous
//
#include <hip/hip_runtime.h>

#define D 64
#define BK_SHIFT 8
#define BK_MASK 255
#define SEGCAP 4096
#define ESLICE 4096

typedef __attribute__((ext_vector_type(8))) short short8;   // 8 bf16 = 4 VGPRs
typedef __attribute__((ext_vector_type(4))) float floatx4;  // MFMA C/D

__device__ __forceinline__ ushort f2bf(float f) {     // fp32 -> bf16, RNE
    unsigned u = __float_as_uint(f);
    u += 0x7fffu + ((u >> 16) & 1u);
    return (ushort)(u >> 16);
}
__device__ __forceinline__ float bf2f(ushort h) {
    return __int_as_float(((unsigned)h) << 16);
}

// ---------------- fused: cast x to bf16 rows (blocks < castb) ---------------------
//                  + bucket counts of dst>>8 (blocks >= castb) ---------------------
// bkcount role ALSO saves its per-slice histogram to scnt[slice][512] so route
// can skip recomputing it (one less 4MB ei pass + 1M LDS atomics).
__global__ void cast_bkcount_kernel(const float* __restrict__ x, ushort* __restrict__ xh,
                                    const int* __restrict__ ei, int* __restrict__ bkcnt,
                                    int* __restrict__ scnt,
                                    int n4, int E, int B, int castb) {
    int bid = blockIdx.x;
    int tid = threadIdx.x;
    if (bid < castb) {                       // ---- cast role
        int i = bid * 256 + tid;
        if (i >= n4) return;
        float4 v = ((const float4*)x)[i];
        ushort4 r;
        r.x = f2bf(v.x); r.y = f2bf(v.y); r.z = f2bf(v.z); r.w = f2bf(v.w);
        ((ushort4*)xh)[i] = r;
        return;
    }
    // ---- bkcount role: per-block LDS hist of dst>>8
    __shared__ int h[512];
    h[tid] = 0; h[tid + 256] = 0;
    __syncthreads();
    int slice = bid - castb;
    int e0 = slice * ESLICE;
#pragma unroll 4
    for (int it = 0; it < ESLICE / 256; ++it) {
        int e = e0 + it * 256 + tid;
        if (e < E) atomicAdd(&h[ei[E + e] >> BK_SHIFT], 1);
    }
    __syncthreads();
    scnt[slice * 512 + tid] = h[tid];            // coalesced slice-hist save
    scnt[slice * 512 + 256 + tid] = h[tid + 256];
    if (tid < B && h[tid]) atomicAdd(&bkcnt[tid], h[tid]);
    int t2 = tid + 256;
    if (t2 < B && h[t2]) atomicAdd(&bkcnt[t2], h[t2]);
}

// ---------------- A2: single-block exclusive scan of bucket counts ----------------
__global__ void bkscan_kernel(const int* __restrict__ bkcnt, int* __restrict__ bkbeg,
                              int* __restrict__ bkcur, int B) {
    __shared__ int wsum[8];
    int tid = threadIdx.x;           // 512 threads
    int lane = tid & 63, w = tid >> 6;
    int c = (tid < B) ? bkcnt[tid] : 0;
    int p = c;
#pragma unroll
    for (int o = 1; o < 64; o <<= 1) {
        int u = __shfl_up(p, o, 64);
        if (lane >= o) p += u;
    }
    if (lane == 63) wsum[w] = p;
    __syncthreads();
    int base = 0;
    for (int ww = 0; ww < w; ++ww) base += wsum[ww];
    int excl = base + p - c;
    if (tid < B) { bkbeg[tid] = excl; bkcur[tid] = excl; }
    if (tid == B - 1) bkbeg[B] = excl + c;   // == E
}

// ---------------- A3: route edges into bucket regions, packed (src<<8)|dstlow -----
// Pass 1 replaced by a 2KB scnt read (histogram saved by cast_bkcount).
__global__ void route_kernel(const int* __restrict__ ei, const int* __restrict__ scnt,
                             int* __restrict__ bkcur, int* __restrict__ bucketed,
                             int E, int B) {
    __shared__ int h[512];
    __shared__ int gb[512];
    int tid = threadIdx.x;
    int slice = blockIdx.x;
    int c0 = scnt[slice * 512 + tid];
    int c1 = scnt[slice * 512 + 256 + tid];
    gb[tid] = c0 ? atomicAdd(&bkcur[tid], c0) : 0;
    gb[tid + 256] = c1 ? atomicAdd(&bkcur[tid + 256], c1) : 0;
    h[tid] = 0; h[tid + 256] = 0;                // per-bucket cursors
    __syncthreads();
    int e0 = slice * ESLICE;
#pragma unroll 4
    for (int it = 0; it < ESLICE / 256; ++it) {  // route (dst slice L2-hot)
        int e = e0 + it * 256 + tid;
        if (e < E) {
            int dst = ei[E + e];
            int key = dst >> BK_SHIFT;
            int src = ei[e];
            int r = atomicAdd(&h[key], 1);
            bucketed[gb[key] + r] = (src << BK_SHIFT) | (dst & BK_MASK);
        }
    }
}

// ---------------- B: per-bucket CSR segment build, all HBM writes coalesced -------
__global__ void csr_kernel(const int* __restrict__ bucketed, const int* __restrict__ bkbeg,
                           int* __restrict__ srclist, int* __restrict__ beg,
                           int* __restrict__ cnt, int* __restrict__ hist, int N) {
    __shared__ int lcnt[256];
    __shared__ int lbeg[256];
    __shared__ int seg[SEGCAP];
    __shared__ int wsum[4];
    __shared__ int lh[64];
    int k = blockIdx.x;
    int tid = threadIdx.x;
    int nd0 = k << BK_SHIFT;
    int nn = min(256, N - nd0);
    int ebeg = bkbeg[k], eend = bkbeg[k + 1];
    int ecnt = eend - ebeg;
    lcnt[tid] = 0;
    if (tid < 64) lh[tid] = 0;
    __syncthreads();
    for (int e = ebeg + tid; e < eend; e += 256)
        atomicAdd(&lcnt[bucketed[e] & BK_MASK], 1);
    __syncthreads();
    int c = lcnt[tid];
    int lane = tid & 63, w = tid >> 6;
    int p = c;
#pragma unroll
    for (int o = 1; o < 64; o <<= 1) {
        int u = __shfl_up(p, o, 64);
        if (lane >= o) p += u;
    }
    if (lane == 63) wsum[w] = p;
    __syncthreads();
    int base = 0;
    for (int ww = 0; ww < w; ++ww) base += wsum[ww];
    int excl = base + p - c;
    lbeg[tid] = excl;
    lcnt[tid] = 0;                               // reuse as fill cursors
    __syncthreads();
    if (ecnt <= SEGCAP) {
        for (int e = ebeg + tid; e < eend; e += 256) {
            int v = bucketed[e];
            int key = v & BK_MASK;
            int pos = lbeg[key] + atomicAdd(&lcnt[key], 1);
            seg[pos] = v >> BK_SHIFT;
        }
        __syncthreads();
        for (int i = tid; i < ecnt; i += 256)
            srclist[ebeg + i] = seg[i];          // coalesced full-line dump
    } else {                                     // overflow fallback (correct, rare)
        for (int e = ebeg + tid; e < eend; e += 256) {
            int v = bucketed[e];
            int key = v & BK_MASK;
            int pos = lbeg[key] + atomicAdd(&lcnt[key], 1);
            srclist[ebeg + pos] = v >> BK_SHIFT;
        }
    }
    __syncthreads();
    if (tid < nn) {
        int dg = lcnt[tid];                      // cursor end == degree
        cnt[nd0 + tid] = dg;
        beg[nd0 + tid] = ebeg + lbeg[tid];
        atomicAdd(&lh[dg < 63 ? dg : 63], 1);
    }
    __syncthreads();
    if (tid < 64 && lh[tid]) atomicAdd(&hist[tid], lh[tid]);
}

// ---------------- scatter nodes into DESCENDING-degree perm ----------------------
__global__ void scatter_kernel(const int* __restrict__ cnt, const int* __restrict__ hist,
                               int* __restrict__ bincur0, int* __restrict__ perm, int N) {
    __shared__ int lh[64];
    __shared__ int lbase[64];
    __shared__ int sbase[64];
    int tid = threadIdx.x;
    if (tid < 64) {
        lh[tid] = 0;
        int c = hist[tid];
        int p = c;
#pragma unroll
        for (int o = 1; o < 64; o <<= 1) {
            int u = __shfl_up(p, o, 64);
            if (tid >= o) p += u;
        }
        sbase[tid] = N - p;            // suffix base: high-degree bins first
    }
    __syncthreads();
    int i = blockIdx.x * blockDim.x + tid;
    int bin = 0, slot = 0;
    if (i < N) {
        int c = cnt[i];
        bin = c < 63 ? c : 63;
        slot = atomicAdd(&lh[bin], 1);
    }
    __syncthreads();
    if (tid < 64 && lh[tid] > 0) lbase[tid] = sbase[tid] + atomicAdd(&bincur0[tid], lh[tid]);
    __syncthreads();
    if (i < N) perm[lbase[bin] + slot] = i;
}

// ---------------- fused SAGE layer: bf16 gather + MFMA combine ----------------
// Latency model (round-9, matches measured 45us): per hop the chain
// srclist->row->consume ~1500cyc runs ~1-deep per wave; 4 waves/SIMD ->
// 6250 groups/1024 SIMDs x 10 hops x 1500cyc ~ 38us. Fix = DEPTH: 4-hop
// batched gather (round-8 body). Round-8 spilled ONLY because (256,4)'s
// 128-reg cap had no slack (baseline 64 + ~46 live batch); (256,3) cap=170
// with measured baseline 76 leaves room. Spill tripwire: WRITE_SIZE must
// stay at ideal 12.8/25.6MB (round-8 spill showed 94MB).

__global__ void __launch_bounds__(256, 3) sage_kernel(
    const ushort* __restrict__ inh,      // bf16 rows [N][64]
    const int* __restrict__ perm,
    const int* __restrict__ beg_, const int* __restrict__ cnt_,
    const int* __restrict__ srclist,
    const float* __restrict__ Wl, const float* __restrict__ bl,
    const float* __restrict__ Wr,
    float* __restrict__ out_f32,         // fp32 out (layer 2) or null
    ushort* __restrict__ out_bf,         // bf16 out (layer 1) or null
    int N, int relu) {
    __shared__ short8 fL[8][64];   // [c*2+s][lane]: B-frag of Wl^T, col-tile c, k-step s
    __shared__ short8 fR[8][64];
    __shared__ float ot[4][16 * 68];     // per-wave out tile, stride 68 (bank spread)
    int tid = threadIdx.x;
    int lane = tid & 63;
    {
        int c = tid >> 6;
        int n = lane & 15;
        int q = lane >> 4;
#pragma unroll
        for (int s = 0; s < 2; ++s) {
            const float* pl = Wl + (c * 16 + n) * D + s * 32 + q * 8;
            const float* pr = Wr + (c * 16 + n) * D + s * 32 + q * 8;
            short8 vl, vr;
#pragma unroll
            for (int j = 0; j < 8; ++j) {
                vl[j] = (short)f2bf(pl[j]);
                vr[j] = (short)f2bf(pr[j]);
            }
            fL[c * 2 + s][lane] = vl;
            fR[c * 2 + s][lane] = vr;
        }
    }
    __syncthreads();

    int m = lane & 15;
    int q = lane >> 4;
    float* otw = &ot[tid >> 6][0];
    float b0 = bl[m], b1 = bl[16 + m], b2 = bl[32 + m], b3 = bl[48 + m];
    int gwave   = blockIdx.x * 4 + (tid >> 6);
    int nwaves  = gridDim.x * 4;
    int ngroups = (N + 15) >> 4;

    for (int g = gwave; g < ngroups; g += nwaves) {
        int base = g * 16;
        bool nv = (base + m) < N;
        int node = nv ? perm[base + m] : 0;
        int beg = nv ? beg_[node] : 0;   // 4 lanes per node share the address
        int deg = nv ? cnt_[node] : 0;

        // wave-max degree (uniform after descending sort except at bin boundaries)
        int md = deg;
        md = max(md, __shfl_xor(md, 1, 64));
        md = max(md, __shfl_xor(md, 2, 64));
        md = max(md, __shfl_xor(md, 4, 64));
        md = max(md, __shfl_xor(md, 8, 64));

        float f0[8], f1[8];
#pragma unroll
        for (int u = 0; u < 8; ++u) { f0[u] = 0.f; f1[u] = 0.f; }

        // batched gather: 4 hops per stage -> 8 parallel row loads in flight
        for (int j = 0; j < md; j += 4) {
            int si0, si1, si2, si3;
            {
                int j0 = j,     i0 = beg + ((j0 < deg) ? j0 : 0);
                int j1 = j + 1, i1 = beg + ((j1 < deg) ? j1 : 0);
                int j2 = j + 2, i2 = beg + ((j2 < deg) ? j2 : 0);
                int j3 = j + 3, i3 = beg + ((j3 < deg) ? j3 : 0);
                si0 = srclist[i0]; si1 = srclist[i1];
                si2 = srclist[i2]; si3 = srclist[i3];
            }
            const ushort* rp0 = inh + (size_t)si0 * D;
            const ushort* rp1 = inh + (size_t)si1 * D;
            const ushort* rp2 = inh + (size_t)si2 * D;
            const ushort* rp3 = inh + (size_t)si3 * D;
            short8 lo0 = *(const short8*)(rp0 + q * 8);
            short8 hi0 = *(const short8*)(rp0 + 32 + q * 8);
            short8 lo1 = *(const short8*)(rp1 + q * 8);
            short8 hi1 = *(const short8*)(rp1 + 32 + q * 8);
            short8 lo2 = *(const short8*)(rp2 + q * 8);
            short8 hi2 = *(const short8*)(rp2 + 32 + q * 8);
            short8 lo3 = *(const short8*)(rp3 + q * 8);
            short8 hi3 = *(const short8*)(rp3 + 32 + q * 8);
            float m0 = (j     < deg) ? 1.f : 0.f;
            float m1 = (j + 1 < deg) ? 1.f : 0.f;
            float m2 = (j + 2 < deg) ? 1.f : 0.f;
            float m3 = (j + 3 < deg) ? 1.f : 0.f;
#pragma unroll
            for (int u = 0; u < 8; ++u) {
                f0[u] = fmaf(m0, bf2f((ushort)lo0[u]), f0[u]);
                f1[u] = fmaf(m0, bf2f((ushort)hi0[u]), f1[u]);
                f0[u] = fmaf(m1, bf2f((ushort)lo1[u]), f0[u]);
                f1[u] = fmaf(m1, bf2f((ushort)hi1[u]), f1[u]);
                f0[u] = fmaf(m2, bf2f((ushort)lo2[u]), f0[u]);
                f1[u] = fmaf(m2, bf2f((ushort)hi2[u]), f1[u]);
                f0[u] = fmaf(m3, bf2f((ushort)lo3[u]), f0[u]);
                f1[u] = fmaf(m3, bf2f((ushort)hi3[u]), f1[u]);
            }
        }

        float scale = (deg > 0) ? 1.0f / (float)deg : 0.0f;
        short8 a0, a1;
#pragma unroll
        for (int u = 0; u < 8; ++u) {
            a0[u] = (short)f2bf(f0[u] * scale);
            a1[u] = (short)f2bf(f1[u] * scale);
        }

        // root rows load directly as A-fragments
        const ushort* rr = inh + (size_t)node * D;
        short8 r0 = *(const short8*)(rr + q * 8);
        short8 r1 = *(const short8*)(rr + 32 + q * 8);

#pragma unroll
        for (int c = 0; c < 4; ++c) {
            float bc = (c == 0) ? b0 : (c == 1) ? b1 : (c == 2) ? b2 : b3;
            floatx4 acc = {bc, bc, bc, bc};
            acc = __builtin_amdgcn_mfma_f32_16x16x32_bf16(a0, fL[c * 2 + 0][lane], acc, 0, 0, 0);
            acc = __builtin_amdgcn_mfma_f32_16x16x32_bf16(a1, fL[c * 2 + 1][lane], acc, 0, 0, 0);
            acc = __builtin_amdgcn_mfma_f32_16x16x32_bf16(r0, fR[c * 2 + 0][lane], acc, 0, 0, 0);
            acc = __builtin_amdgcn_mfma_f32_16x16x32_bf16(r1, fR[c * 2 + 1][lane], acc, 0, 0, 0);
#pragma unroll
            for (int r = 0; r < 4; ++r) {
                float v = acc[r];
                if (relu) v = fmaxf(v, 0.f);
                otw[(q * 4 + r) * 68 + c * 16 + m] = v;   // stage in LDS (wave-private)
            }
        }

        // full-row writeout: 4 lanes per node row, line-complete stores
        int rho = lane >> 2;                 // node slot 0..15
        int q4  = lane & 3;                  // quarter of the row
        int onode = __shfl(node, rho, 64);
        const float* sp = &otw[rho * 68 + q4 * 16];
        if (base + rho < N) {
            if (out_bf) {
                uint u[8];
#pragma unroll
                for (int j = 0; j < 8; ++j)
                    u[j] = (uint)f2bf(sp[2 * j]) | ((uint)f2bf(sp[2 * j + 1]) << 16);
                uint4* dp = (uint4*)(out_bf + (size_t)onode * D + q4 * 16);
                uint4 w0 = {u[0], u[1], u[2], u[3]};
                uint4 w1 = {u[4], u[5], u[6], u[7]};
                dp[0] = w0; dp[1] = w1;      // 32B/lane, 128B/row contiguous
            } else {
                float4* dp = (float4*)(out_f32 + (size_t)onode * D + q4 * 16);
                const float4* s4 = (const float4*)sp;
                dp[0] = s4[0]; dp[1] = s4[1]; dp[2] = s4[2]; dp[3] = s4[3];  // 64B/lane
            }
        }
    }
}

extern "C" void kernel_launch(void* const* d_in, const int* in_sizes, int n_in,
                              void* d_out, int out_size, void* d_ws, size_t ws_size,
                              hipStream_t stream) {
    const float* x   = (const float*)d_in[0];
    const int*   ei  = (const int*)d_in[1];
    const float* W1l = (const float*)d_in[2];
    const float* b1l = (const float*)d_in[3];
    const float* W1r = (const float*)d_in[4];
    const float* W2l = (const float*)d_in[5];
    const float* b2l = (const float*)d_in[6];
    const float* W2r = (const float*)d_in[7];
    float* out = (float*)d_out;

    int N = in_sizes[0] / D;   // 100000
    int E = in_sizes[1] / 2;   // 1000000
    int B = (N + BK_MASK) >> BK_SHIFT;   // 391 buckets
    int eslices = (E + ESLICE - 1) / ESLICE;   // 245

    char* ws = (char*)d_ws;
    // Layout (bytes):
    //   [0, N*D*2)         xh : bf16 x rows
    //   [N*D*2, 2*N*D*2)   hh : bf16 h rows; `bucketed` (E ints = 4MB < 12.8MB)
    //                          aliases here -- dead before sage1 writes hh
    //   then srclist (+slack), beg, cnt, perm.
    //   hist, bincur0, bkcnt are contiguous and cleared by ONE memset.
    //   scnt = per-slice bucket histograms (eslices x 512 ints, ~500KB).
    ushort* xh = (ushort*)ws;
    ushort* hh = xh + (size_t)N * D;
    int*   bucketed = (int*)hh;                           // E ints (alias hh)
    int*   srclist  = (int*)(ws + (size_t)2 * N * D * 2); // E ints + 64 slack
    int*   beg      = srclist + E + 64;                   // N ints
    int*   cnt      = beg + N;                            // N ints
    int*   perm     = cnt + N;                            // N ints
    int*   hist     = perm + N;                           // 64 ints (memset group)
    int*   bincur0  = hist + 64;                          // 64 ints (memset group)
    int*   bkcnt    = bincur0 + 64;                       // 512 ints (memset group)
    int*   bkbeg    = bkcnt + 512;                        // 513 ints
    int*   bkcur    = bkbeg + 513;                        // 512 ints
    int*   scnt     = bkcur + 512;                        // eslices*512 ints

    (void)hipMemsetAsync(hist, 0, (64 + 64 + 512) * sizeof(int), stream);

    int n4 = N * D / 4;
    int castb = (n4 + 255) / 256;
    cast_bkcount_kernel<<<castb + eslices, 256, 0, stream>>>(x, xh, ei, bkcnt, scnt,
                                                             n4, E, B, castb);
    bkscan_kernel<<<1, 512, 0, stream>>>(bkcnt, bkbeg, bkcur, B);
    route_kernel<<<eslices, 256, 0, stream>>>(ei, scnt, bkcur, bucketed, E, B);
    csr_kernel<<<B, 256, 0, stream>>>(bucketed, bkbeg, srclist, beg, cnt, hist, N);
    int nblocks = (N + 255) / 256;
    scatter_kernel<<<nblocks, 256, 0, stream>>>(cnt, hist, bincur0, perm, N);

    int ngroups = (N + 15) / 16;              // 6250
    int sblocks = (ngroups + 3) / 4;          // 1 group per wave, HW backfill
    // layer 1: hh(bf16) = relu(mean_agg(xh)@W1l^T + b1l + xh@W1r^T)
    sage_kernel<<<sblocks, 256, 0, stream>>>(xh, perm, beg, cnt, srclist,
                                             W1l, b1l, W1r, nullptr, hh, N, 1);
    // layer 2: out(fp32) = mean_agg(hh)@W2l^T + b2l + hh@W2r^T
    sage_kernel<<<sblocks, 256, 0, stream>>>(hh, perm, beg, cnt, srclist,
                                             W2l, b2l, W2r, out, nullptr, N, 0);
}